// Round 8
// baseline (554.975 us; speedup 1.0000x reference)
//
#include <hip/hip_runtime.h>

#define NTG 128
#define NSTEPS 8191          // SEQ_LEN-1
#define GCH 1024             // chunks
#define LCH 8                // emissions per chunk (leaf + 7 steps)
#define MATF16 (NTG*NTG)
#define NB1 (GCH/8)          // 128 matrices after the single combine level

typedef _Float16 half8v  __attribute__((ext_vector_type(8)));
typedef _Float16 half4v  __attribute__((ext_vector_type(4)));
typedef float    float4v __attribute__((ext_vector_type(4)));

// swizzled index into a [128][128] f16 LDS tile (element units).
// XOR bits 3..6 with row bits 0..3; preserves 4- and 8-elem aligned runs.
__device__ __forceinline__ int su(int row, int col){
  return (row*NTG + col) ^ ((row & 15) << 3);
}

__device__ __forceinline__ float wave_max(float v){
#pragma unroll
  for (int m = 32; m >= 1; m >>= 1) v = fmaxf(v, __shfl_xor(v, m));
  return v;
}
__device__ __forceinline__ float wave_sum(float v){
#pragma unroll
  for (int m = 32; m >= 1; m >>= 1) v += __shfl_xor(v, m);
  return v;
}
__device__ __forceinline__ float red8(const float* rg){
  const float4v r0 = *(const float4v*)rg;
  const float4v r1 = *(const float4v*)(rg+4);
  return fmaxf(fmaxf(fmaxf(r0[0],r0[1]),fmaxf(r0[2],r0[3])),
               fmaxf(fmaxf(r1[0],r1[1]),fmaxf(r1[2],r1[3])));
}

// ---------------- kernel 0: En = exp(T) f16, Et = exp(T)^T f16 ----------------
__global__ void k_prep(const float* __restrict__ T, _Float16* __restrict__ En,
                       _Float16* __restrict__ Et){
  const int idx = blockIdx.x*256 + threadIdx.x;   // 16384
  const int i = idx >> 7, j = idx & 127;
  const float v = __expf(T[idx]);
  En[idx] = (_Float16)v;
  Et[j*NTG + i] = (_Float16)v;      // Et[j][i] = E[i][j]
}

// ---------------- kernel 1: per-chunk transfer matrices ----------------
// 8 waves: wave (wr,wc)=(wv>>2, wv&3) owns D rows j in [wr*64,+64), cols i in
// [wc*32,+32). Single X buffer (32 KB), 2 barriers/step. eh*pscale applied on
// D in f32 (ehd). X stored raw-scaled (max <= ~11520, f16-safe). Pt = M^T/max.
__global__ __launch_bounds__(512, 8)
void k_chunks(const int* __restrict__ x, const float* __restrict__ emit,
              const _Float16* __restrict__ En, const _Float16* __restrict__ Et,
              _Float16* __restrict__ Pt, double* __restrict__ scale)
{
  __shared__ _Float16 X[MATF16];    // 32 KB
  __shared__ float red_g[2][8];

  const int t = threadIdx.x, lane = t & 63, wv = t >> 6;
  const int l15 = lane & 15, g4 = lane >> 4;
  const int wr = wv >> 2, wc = wv & 3;
  const int g = blockIdx.x, s0 = g*LCH;
  const int nst = min(LCH, NSTEPS - s0);          // 8 (last chunk 7)

  // A = E^T fragments: A row j = wr*64+rt*16+l15, k-slot = ks*32+g4*8+[0..7]
  half8v aE[4][4];
#pragma unroll
  for (int rt=0; rt<4; ++rt){
    const int j = wr*64 + rt*16 + l15;
#pragma unroll
    for (int ks=0; ks<4; ++ks)
      aE[rt][ks] = *(const half8v*)(Et + j*NTG + ks*32 + g4*8);
  }

  const int tokv = x[1 + s0 + min(lane & 7, nst-1)];   // lanes 0..7 hold tokens

  double cacc = 0.0;
  // leaf: X = En .* exp(emit0 - m0) / 128
  {
    const int tok0 = __shfl(tokv, 0);
    const float2 e0 = *(const float2*)(emit + (size_t)tok0*NTG + lane*2);
    const float m0 = wave_max(fmaxf(e0.x, e0.y));
    const float sa = __expf(e0.x - m0)*0.0078125f;
    const float sb = __expf(e0.y - m0)*0.0078125f;
    const int j0 = lane*2;
    const unsigned* ens = (const unsigned*)En;
#pragma unroll
    for (int it=0; it<16; ++it){
      const int idx = it*512 + t;
      const int i = idx >> 6;
      union { unsigned u; _Float16 h[2]; } pk;
      pk.u = ens[idx];
      pk.h[0] = (_Float16)((float)pk.h[0]*sa);
      pk.h[1] = (_Float16)((float)pk.h[1]*sb);
      *(unsigned*)&X[su(i, j0)] = pk.u;
    }
    if (t==0) cacc = (double)m0 + 4.852030263919617;   // + log 128
    if (t<8) red_g[0][t] = 1.0f;
  }
  __syncthreads();

  float4v accv[4][2];
  for (int s=1; s<nst; ++s){
    const int tok = __shfl(tokv, s);
    const float* er = emit + (size_t)tok*NTG;
    const float2 e2 = *(const float2*)(er + lane*2);
    const float m = wave_max(fmaxf(e2.x, e2.y));
    const float gprev = red8(&red_g[(s-1)&1][0]);
    const float ps = 1.0f/gprev;
    if (t==0) cacc += (double)m + (double)__logf(gprev);

    // ehp[rt][r] = exp(er[j]-m)*ps for D rows j = wr*64+rt*16+g4*4+r
    float ehp[4][4];
#pragma unroll
    for (int rt=0; rt<4; ++rt)
#pragma unroll
      for (int r=0; r<4; ++r)
        ehp[rt][r] = __expf(er[wr*64 + rt*16 + g4*4 + r] - m) * ps;

#pragma unroll
    for (int rt=0;rt<4;++rt)
#pragma unroll
      for (int ct=0;ct<2;++ct) accv[rt][ct] = (float4v){0.f,0.f,0.f,0.f};

#pragma unroll
    for (int ct=0; ct<2; ++ct){
      const int c = wc*32 + ct*16 + l15;
      half8v bf[4];
#pragma unroll
      for (int ks=0;ks<4;++ks)
        bf[ks] = *(const half8v*)&X[su(c, ks*32 + g4*8)];   // B[k][c]=M[c][k]
#pragma unroll
      for (int rt=0;rt<4;++rt)
#pragma unroll
        for (int ks=0;ks<4;++ks)
          accv[rt][ct] = __builtin_amdgcn_mfma_f32_16x16x32_f16(aE[rt][ks], bf[ks], accv[rt][ct], 0,0,0);
    }
    __syncthreads();                          // bar1: all X reads done

    float gm = 0.f;
#pragma unroll
    for (int rt=0;rt<4;++rt)
#pragma unroll
      for (int ct=0;ct<2;++ct){
        half4v h;
#pragma unroll
        for (int r=0;r<4;r++){
          const float v = accv[rt][ct][r]*ehp[rt][r];
          gm = fmaxf(gm, v);
          h[r] = (_Float16)v;
        }
        *(half4v*)&X[su(wc*32 + ct*16 + l15, wr*64 + rt*16 + g4*4)] = h;
      }
    gm = wave_max(gm);
    if (lane==0) red_g[s&1][wv] = gm;
    __syncthreads();                          // bar2: X writes + red_g visible
  }

  // store Pt[g] = M^T normalized to max 1
  const float gF = red8(&red_g[(nst-1)&1][0]);
  const float inv = 1.0f/gF;
  unsigned* pt = (unsigned*)(Pt + (size_t)g*MATF16);
  const int ii = lane*2;
#pragma unroll
  for (int it=0; it<16; ++it){
    const int uidx = it*512 + t;
    const int jj = uidx >> 6;
    union { unsigned u; _Float16 h[2]; } pk;
    pk.h[0] = (_Float16)((float)X[su(ii,   jj)]*inv);
    pk.h[1] = (_Float16)((float)X[su(ii+1, jj)]*inv);
    pt[uidx] = pk.u;
  }
  if (t==0) scale[g] = cacc + (double)__logf(gF);
}

// ---------------- kernel 2: fan-in-8 combine: R <- R*Y_mi, f32 renorm ----------------
__global__ __launch_bounds__(512, 2)
void k_comb8(const _Float16* __restrict__ Pt_in, const double* __restrict__ Sin,
             _Float16* __restrict__ Pt_out, double* __restrict__ Sout)
{
  __shared__ _Float16 X[MATF16];
  __shared__ float red_g[2][8];
  const int t = threadIdx.x, lane = t & 63, wv = t >> 6;
  const int l15 = lane & 15, g4 = lane >> 4;
  const int wr = wv >> 2, wc = wv & 3;
  const int p = blockIdx.x;
  const _Float16* __restrict__ base = Pt_in + (size_t)p*8*MATF16;

  // stage X = M_{8p} (normal) from its transposed image
  {
    const unsigned* src = (const unsigned*)base;
    const int i0 = lane*2;
#pragma unroll
    for (int it=0; it<16; ++it){
      const int pos = it*512 + t;
      union { unsigned u; _Float16 h[2]; } pk;
      pk.u = src[pos];
      const int jj = pos >> 6;
      X[su(i0,   jj)] = pk.h[0];
      X[su(i0+1, jj)] = pk.h[1];
    }
    if (t<8) red_g[0][t] = 1.0f;
  }
  __syncthreads();

  // preload A (rows of Yt, contiguous) for mi=1
  half8v aB[4][4];
#pragma unroll
  for (int rt=0;rt<4;++rt)
#pragma unroll
    for (int ks=0;ks<4;++ks)
      aB[rt][ks] = *(const half8v*)(base + MATF16 + (size_t)(wr*64+rt*16+l15)*NTG + ks*32 + g4*8);

  double slog = 0.0;
  float4v accv[4][2];
#pragma unroll 1
  for (int mi=1; mi<8; ++mi){
#pragma unroll
    for (int rt=0;rt<4;++rt)
#pragma unroll
      for (int ct=0;ct<2;++ct) accv[rt][ct] = (float4v){0.f,0.f,0.f,0.f};

    const _Float16* __restrict__ Xs = X;
#pragma unroll
    for (int ct=0; ct<2; ++ct){
      const int c = wc*32 + ct*16 + l15;
      half8v bf[4];
#pragma unroll
      for (int ks=0;ks<4;++ks)
        bf[ks] = *(const half8v*)&Xs[su(c, ks*32 + g4*8)];
#pragma unroll
      for (int rt=0;rt<4;++rt)
#pragma unroll
        for (int ks=0;ks<4;++ks)
          accv[rt][ct] = __builtin_amdgcn_mfma_f32_16x16x32_f16(aB[rt][ks], bf[ks], accv[rt][ct], 0,0,0);
    }

    half8v aBn[4][4];
    if (mi<7){                                 // prefetch next A
#pragma unroll
      for (int rt=0;rt<4;++rt)
#pragma unroll
        for (int ks=0;ks<4;++ks)
          aBn[rt][ks] = *(const half8v*)(base + (size_t)(mi+1)*MATF16 + (size_t)(wr*64+rt*16+l15)*NTG + ks*32 + g4*8);
    }
    __syncthreads();                           // bar1: reads done

    const float gprev = red8(&red_g[(mi-1)&1][0]);
    const float ps = 1.0f/gprev;
    if (t==0) slog += (double)__logf(gprev);
    float gm = 0.f;
#pragma unroll
    for (int rt=0;rt<4;++rt)
#pragma unroll
      for (int ct=0;ct<2;++ct){
        half4v h;
#pragma unroll
        for (int r=0;r<4;r++){
          const float v = accv[rt][ct][r]*ps;
          gm = fmaxf(gm, v);
          h[r] = (_Float16)v;
        }
        *(half4v*)&X[su(wc*32 + ct*16 + l15, wr*64 + rt*16 + g4*4)] = h;
      }
    gm = wave_max(gm);
    if (lane==0) red_g[mi&1][wv] = gm;
    __syncthreads();                           // bar2

    if (mi<7){
#pragma unroll
      for (int rt=0;rt<4;++rt)
#pragma unroll
        for (int ks=0;ks<4;++ks) aB[rt][ks] = aBn[rt][ks];
    }
  }

  const float gF = red8(&red_g[1][0]);         // (7)&1
  const float inv = 1.0f/gF;
  unsigned* pt = (unsigned*)(Pt_out + (size_t)p*MATF16);
  const int ii = lane*2;
#pragma unroll
  for (int it=0; it<16; ++it){
    const int uidx = it*512 + t;
    const int jj = uidx >> 6;
    union { unsigned u; _Float16 h[2]; } pk;
    pk.h[0] = (_Float16)((float)X[su(ii,   jj)]*inv);
    pk.h[1] = (_Float16)((float)X[su(ii+1, jj)]*inv);
    pt[uidx] = pk.u;
  }
  if (t==0){
    double ssum = slog + (double)__logf(gF);
#pragma unroll
    for (int q=0;q<8;q++) ssum += Sin[p*8+q];
    Sout[p] = ssum;
  }
}

// ---------------- kernel 3: renormalizing matvec chain over 128 mats + lse ----------------
// 512 thr: 4 per row (q = t&3 handles 32 cols). Per-iter renorm by max(u)
// computed inside the dot loop (quad shuffles, no extra barrier).
__global__ void k_final(const _Float16* __restrict__ PtB, const double* __restrict__ scB,
                        const float* __restrict__ T, float* __restrict__ out)
{
  __shared__ float u[2][NTG];
  __shared__ double sredd[8];
  __shared__ float red[8], red2[8];
  const int t = threadIdx.x, lane = t & 63, wv = t >> 6;

  double ss = (t < NB1) ? scB[t] : 0.0;
#pragma unroll
  for (int m=32; m>=1; m>>=1) ss += __shfl_xor(ss, m);
  if (lane==0) sredd[wv] = ss;

  if (t < NTG) u[0][t] = (t==0) ? 1.0f : 0.0f;   // e_START

  const int row = t >> 2, q = t & 3;
  const _Float16* base = PtB + (size_t)row*NTG + q*32;
  half8v cb[4], nb[4];
#pragma unroll
  for (int v=0; v<4; ++v) cb[v] = *(const half8v*)(base + v*8);
  __syncthreads();

  double lacc = 0.0;
  int cur = 0;
  for (int k=0; k<NB1; ++k){
    if (k+1 < NB1){
      const _Float16* nx = base + (size_t)(k+1)*MATF16;
#pragma unroll
      for (int v=0; v<4; ++v) nb[v] = *(const half8v*)(nx + v*8);
    }
    float dot = 0.f, mloc = 0.f;
#pragma unroll
    for (int v=0; v<4; ++v)
#pragma unroll
      for (int e=0; e<8; ++e){
        const float uv = u[cur][q*32 + v*8 + e];
        dot  = fmaf((float)cb[v][e], uv, dot);
        mloc = fmaxf(mloc, uv);
      }
    dot += __shfl_xor(dot, 1);  dot += __shfl_xor(dot, 2);
    mloc = fmaxf(mloc, __shfl_xor(mloc, 1));
    mloc = fmaxf(mloc, __shfl_xor(mloc, 2));
    if (q==0) u[cur^1][row] = dot / mloc;      // renorm: stored max stays O(1..128)
    if (t==0) lacc += (double)__logf(mloc);
    __syncthreads();
#pragma unroll
    for (int v=0; v<4; ++v) cb[v] = nb[v];
    cur ^= 1;
  }

  const float val = (t < NTG) ? (__logf(u[cur][t]) + T[t*NTG + 1]) : -3.0e38f;
  float mx = wave_max(val);
  if (lane==0) red[wv] = mx;
  __syncthreads();
  mx = fmaxf(fmaxf(fmaxf(red[0],red[1]),fmaxf(red[2],red[3])),
             fmaxf(fmaxf(red[4],red[5]),fmaxf(red[6],red[7])));
  const float e = (t < NTG) ? __expf(val - mx) : 0.f;
  const float sE = wave_sum(e);
  if (lane==0) red2[wv] = sE;
  __syncthreads();
  if (t==0){
    float sumE = 0.f;
#pragma unroll
    for (int q2=0;q2<8;q2++) sumE += red2[q2];
    double ssum = 0.0;
#pragma unroll
    for (int q2=0;q2<8;q2++) ssum += sredd[q2];
    out[0] = (float)((double)mx + log((double)sumE) + lacc + ssum);
  }
}

extern "C" void kernel_launch(void* const* d_in, const int* in_sizes, int n_in,
                              void* d_out, int out_size, void* d_ws, size_t ws_size,
                              hipStream_t stream)
{
  const int*   x    = (const int*)d_in[0];
  const float* emit = (const float*)d_in[1];
  const float* T    = (const float*)d_in[2];
  float* out = (float*)d_out;

  // ws (f16): En[1] Et[1] PtA[1024] PtB[128] | dbl scA[1024] scB[128]  (~36.4 MB)
  _Float16* En  = (_Float16*)d_ws;
  _Float16* Et  = En  + MATF16;
  _Float16* PtA = Et  + MATF16;
  _Float16* PtB = PtA + (size_t)GCH*MATF16;
  double* scA = (double*)(PtB + (size_t)NB1*MATF16);
  double* scB = scA + GCH;

  k_prep<<<64, 256, 0, stream>>>(T, En, Et);
  k_chunks<<<GCH, 512, 0, stream>>>(x, emit, En, Et, PtA, scA);
  k_comb8<<<NB1, 512, 0, stream>>>(PtA, scA, PtB, scB);
  k_final<<<1, 512, 0, stream>>>(PtB, scB, T, out);
}